// Round 1
// baseline (813.271 us; speedup 1.0000x reference)
//
#include <hip/hip_runtime.h>
#include <hip/hip_fp16.h>

#define B_SZ 4096
#define I_SZ 2048
#define H_SZ 2048
#define K_SZ 4096   // I + H
#define N_SZ 8192   // 4 * H

typedef _Float16 half8_t __attribute__((ext_vector_type(8)));
typedef _Float16 half4_t __attribute__((ext_vector_type(4)));
typedef float    f32x4   __attribute__((ext_vector_type(4)));

typedef const void __attribute__((address_space(1)))* gas_ptr;
typedef void       __attribute__((address_space(3)))* las_ptr;

__device__ __forceinline__ void async_load16(const void* g, void* l) {
    // width-16 global->LDS DMA; LDS dest is wave-uniform base + lane*16
    __builtin_amdgcn_global_load_lds((gas_ptr)g, (las_ptr)l, 16, 0, 0);
}

// ---------------------------------------------------------------------------
// Kernel 1: combined = concat(x, h) cast to fp16, row-major [4096][4096]
// ---------------------------------------------------------------------------
__global__ void cast_combined_kernel(const float* __restrict__ x,
                                     const float* __restrict__ h,
                                     _Float16* __restrict__ A) {
    int idx = blockIdx.x * 256 + threadIdx.x;   // 0 .. 4M-1, one float4 each
    int b   = idx >> 10;                        // row
    int c4  = idx & 1023;                       // float4 index within row
    const float* src = (c4 < 512) ? (x + (size_t)b * I_SZ + c4 * 4)
                                  : (h + (size_t)b * H_SZ + (c4 - 512) * 4);
    f32x4 v = *(const f32x4*)src;
    half4_t o = { (_Float16)v[0], (_Float16)v[1], (_Float16)v[2], (_Float16)v[3] };
    *(half4_t*)(A + (size_t)b * K_SZ + c4 * 4) = o;
}

// ---------------------------------------------------------------------------
// Kernel 2: Wt[n][k] = (fp16) W[k][n]   — W is [4096][8192] fp32 row-major
// 64x64 tiles via LDS (pad 65 to keep bank aliasing <= 2-way, which is free)
// ---------------------------------------------------------------------------
__global__ void transpose_cast_W(const float* __restrict__ W,
                                 _Float16* __restrict__ Wt) {
    __shared__ _Float16 tile[64][65];
    int nt = blockIdx.x;          // 0..127  (N/64)
    int kt = blockIdx.y;          // 0..63   (K/64)
    int tx = threadIdx.x & 63;
    int tg = threadIdx.x >> 6;    // 0..3
#pragma unroll
    for (int r = 0; r < 16; ++r) {
        int kl = r * 4 + tg;      // k_local
        float v = W[(size_t)(kt * 64 + kl) * N_SZ + nt * 64 + tx];
        tile[kl][tx] = (_Float16)v;
    }
    __syncthreads();
#pragma unroll
    for (int r = 0; r < 16; ++r) {
        int nl = r * 4 + tg;      // n_local
        Wt[(size_t)(nt * 64 + nl) * K_SZ + kt * 64 + tx] = tile[tx][nl];
    }
}

// ---------------------------------------------------------------------------
// Kernel 3: GEMM  G[m][n] = sum_k A[m][k] * Wt[n][k]   (fp16 in, fp32 out)
// m97 structure: 128x128 tile, BK=32, global_load_lds(16B) staging,
// 4 waves each owning a 64x64 quadrant = 4x4 MFMA 16x16x32 tiles.
// ---------------------------------------------------------------------------
__global__ __launch_bounds__(256)
void gemm_kernel(const _Float16* __restrict__ A,
                 const _Float16* __restrict__ Wt,
                 float* __restrict__ G) {
    __shared__ _Float16 sA[128 * 32];   // [row m][k] 64B rows
    __shared__ _Float16 sB[128 * 32];   // [row n][k]
    const int t    = threadIdx.x;
    const int wave = t >> 6;
    const int lane = t & 63;
    const int m0 = blockIdx.y * 128;
    const int n0 = blockIdx.x * 128;
    const int wm = (wave >> 1) * 64;    // quadrant row base
    const int wn = (wave & 1) * 64;     // quadrant col base

    f32x4 acc[4][4] = {};

    // staging addressing: LDS linear order == lane order (wave-uniform base)
    const int srow = wave * 16 + (lane >> 2);      // 0..63 per issue
    const int scol = (lane & 3) * 8;               // fp16 element offset
    const _Float16* gA0 = A  + (size_t)(m0 + srow) * K_SZ + scol;
    const _Float16* gB0 = Wt + (size_t)(n0 + srow) * K_SZ + scol;
    char* lA = (char*)sA + wave * 1024;            // wave-uniform
    char* lB = (char*)sB + wave * 1024;

    const int lm = lane & 15;            // fragment row (A) / row-n (B)
    const int kq = (lane >> 4) * 8;      // fragment k offset

    for (int k0 = 0; k0 < K_SZ; k0 += 32) {
        async_load16(gA0 + k0,             lA);
        async_load16(gA0 + 64 * K_SZ + k0, lA + 4096);
        async_load16(gB0 + k0,             lB);
        async_load16(gB0 + 64 * K_SZ + k0, lB + 4096);
        __syncthreads();   // drains vmcnt before barrier (compiler-enforced)

        half8_t af[4], bf[4];
#pragma unroll
        for (int i = 0; i < 4; ++i)
            af[i] = *(const half8_t*)(sA + (wm + i * 16 + lm) * 32 + kq);
#pragma unroll
        for (int i = 0; i < 4; ++i)
            bf[i] = *(const half8_t*)(sB + (wn + i * 16 + lm) * 32 + kq);
#pragma unroll
        for (int mi = 0; mi < 4; ++mi)
#pragma unroll
            for (int ni = 0; ni < 4; ++ni)
                acc[mi][ni] = __builtin_amdgcn_mfma_f32_16x16x32_f16(
                    af[mi], bf[ni], acc[mi][ni], 0, 0, 0);
        __syncthreads();
    }

    // epilogue: C/D layout col=lane&15, row=(lane>>4)*4+reg
    const int cr = (lane >> 4) * 4;
    const int cc = lane & 15;
#pragma unroll
    for (int mi = 0; mi < 4; ++mi)
#pragma unroll
        for (int ni = 0; ni < 4; ++ni)
#pragma unroll
            for (int r = 0; r < 4; ++r) {
                int row = m0 + wm + mi * 16 + cr + r;
                int col = n0 + wn + ni * 16 + cc;
                G[(size_t)row * N_SZ + col] = acc[mi][ni][r];
            }
}

// ---------------------------------------------------------------------------
// Kernel 4: sLSTM pointwise. gates split [z | i | f | o] along N.
// out = stack([h_t, c_t, n_t, m_t])
// ---------------------------------------------------------------------------
__global__ void eltwise_kernel(const float* __restrict__ G,
                               const float* __restrict__ Bias,
                               const float* __restrict__ c,
                               const float* __restrict__ n,
                               const float* __restrict__ m,
                               float* __restrict__ out) {
    const size_t BH = (size_t)B_SZ * H_SZ;
    int idx = blockIdx.x * 256 + threadIdx.x;   // 0 .. 2M-1, one float4 each
    int b  = idx >> 9;                          // row (2048/4 = 512 f4/row)
    int j4 = (idx & 511) * 4;
    const float* gr = G + (size_t)b * N_SZ;
    f32x4 zt = *(const f32x4*)(gr + j4);
    f32x4 it = *(const f32x4*)(gr + H_SZ + j4);
    f32x4 ft = *(const f32x4*)(gr + 2 * H_SZ + j4);
    f32x4 ot = *(const f32x4*)(gr + 3 * H_SZ + j4);
    f32x4 bz = *(const f32x4*)(Bias + j4);
    f32x4 bi = *(const f32x4*)(Bias + H_SZ + j4);
    f32x4 bf = *(const f32x4*)(Bias + 2 * H_SZ + j4);
    f32x4 bo = *(const f32x4*)(Bias + 3 * H_SZ + j4);
    f32x4 cv = *(const f32x4*)(c + (size_t)b * H_SZ + j4);
    f32x4 nv = *(const f32x4*)(n + (size_t)b * H_SZ + j4);
    f32x4 mv = *(const f32x4*)(m + (size_t)b * H_SZ + j4);
    f32x4 hR, cR, nR, mR;
#pragma unroll
    for (int q = 0; q < 4; ++q) {
        float z  = zt[q] + bz[q];
        float i  = it[q] + bi[q];
        float f  = ft[q] + bf[q];
        float o  = ot[q] + bo[q];
        float z_t = tanhf(z);
        float f_t = 1.0f / (1.0f + expf(-f));
        float o_t = 1.0f / (1.0f + expf(-o));
        float ls  = fminf(f, 0.0f) - log1pf(expf(-fabsf(f)));  // log_sigmoid(f)
        float m_t = fmaxf(ls + mv[q], i);
        float ip  = expf(i - m_t);
        float c_t = f_t * cv[q] + ip * z_t;
        float n_t = f_t * nv[q] + ip;
        float h_t = o_t * (c_t / n_t);
        hR[q] = h_t; cR[q] = c_t; nR[q] = n_t; mR[q] = m_t;
    }
    size_t off = (size_t)b * H_SZ + j4;
    *(f32x4*)(out + off)          = hR;
    *(f32x4*)(out + BH + off)     = cR;
    *(f32x4*)(out + 2 * BH + off) = nR;
    *(f32x4*)(out + 3 * BH + off) = mR;
}

// ---------------------------------------------------------------------------
extern "C" void kernel_launch(void* const* d_in, const int* in_sizes, int n_in,
                              void* d_out, int out_size, void* d_ws, size_t ws_size,
                              hipStream_t stream) {
    const float* x    = (const float*)d_in[0];
    const float* h    = (const float*)d_in[1];
    const float* c    = (const float*)d_in[2];
    const float* n    = (const float*)d_in[3];
    const float* m    = (const float*)d_in[4];
    const float* W    = (const float*)d_in[5];
    const float* Bias = (const float*)d_in[6];
    float* out = (float*)d_out;

    // ws layout: Wt fp16 (64 MiB) | combined fp16 (32 MiB) | gates fp32 (128 MiB)
    const size_t WT_BYTES = (size_t)N_SZ * K_SZ * 2;       //  67108864
    const size_t A_BYTES  = (size_t)B_SZ * K_SZ * 2;       //  33554432
    const size_t G_BYTES  = (size_t)B_SZ * N_SZ * 4;       // 134217728
    if (ws_size < WT_BYTES + A_BYTES + G_BYTES) return;    // fail fast -> absmax error signals ws too small

    char* ws = (char*)d_ws;
    _Float16* Wt = (_Float16*)ws;
    _Float16* A  = (_Float16*)(ws + WT_BYTES);
    float*    G  = (float*)(ws + WT_BYTES + A_BYTES);

    cast_combined_kernel<<<16384, 256, 0, stream>>>(x, h, A);
    transpose_cast_W<<<dim3(128, 64), 256, 0, stream>>>(W, Wt);
    gemm_kernel<<<dim3(64, 32), 256, 0, stream>>>(A, Wt, G);
    eltwise_kernel<<<8192, 256, 0, stream>>>(G, Bias, c, n, m, out);
}

// Round 2
// 747.443 us; speedup vs baseline: 1.0881x; 1.0881x over previous
//
#include <hip/hip_runtime.h>
#include <hip/hip_fp16.h>

#define M_SZ 4096
#define I_SZ 2048
#define H_SZ 2048
#define K_SZ 4096   // I + H
#define N_SZ 8192   // 4 * H

typedef _Float16 half8_t __attribute__((ext_vector_type(8)));
typedef _Float16 half4_t __attribute__((ext_vector_type(4)));
typedef float    f32x4   __attribute__((ext_vector_type(4)));

typedef const void __attribute__((address_space(1)))* gas_ptr;
typedef void       __attribute__((address_space(3)))* las_ptr;

__device__ __forceinline__ void async_load16(const void* g, void* l) {
    // width-16 global->LDS DMA; LDS dest is wave-uniform base + lane*16
    __builtin_amdgcn_global_load_lds((gas_ptr)g, (las_ptr)l, 16, 0, 0);
}

__device__ __forceinline__ float fexp(float x) {
    return __builtin_amdgcn_exp2f(x * 1.44269504088896340736f);
}
__device__ __forceinline__ float frcp(float x) { return __builtin_amdgcn_rcpf(x); }
__device__ __forceinline__ float flog1p(float t) {
    // log(1+t), t in (0,1]; log2 then scale. abs err ~1e-7 at small t via 1+t rounding.
    return __builtin_amdgcn_logf(1.0f + t) * 0.69314718055994530942f;
}

// ---------------------------------------------------------------------------
// Kernel 1: combined = concat(x, h) cast to fp16, row-major [4096][4096]
// ---------------------------------------------------------------------------
__global__ void cast_combined_kernel(const float* __restrict__ x,
                                     const float* __restrict__ h,
                                     _Float16* __restrict__ A) {
    int idx = blockIdx.x * 256 + threadIdx.x;   // one float4 each
    int b   = idx >> 10;
    int c4  = idx & 1023;
    const float* src = (c4 < 512) ? (x + (size_t)b * I_SZ + c4 * 4)
                                  : (h + (size_t)b * H_SZ + (c4 - 512) * 4);
    f32x4 v = *(const f32x4*)src;
    half4_t o = { (_Float16)v[0], (_Float16)v[1], (_Float16)v[2], (_Float16)v[3] };
    *(half4_t*)(A + (size_t)b * K_SZ + c4 * 4) = o;
}

// ---------------------------------------------------------------------------
// Kernel 2: Wt[n][k] = (fp16) W[k][n].  LDS-free: column loads are coalesced
// across lanes (16 consecutive n per 64B segment); stores are 16B half8 with
// 4 lanes covering 64B contiguous per output row.
// ---------------------------------------------------------------------------
__global__ void transpose_cast_W(const float* __restrict__ W,
                                 _Float16* __restrict__ Wt) {
    int t  = threadIdx.x;
    int n  = blockIdx.x * 64 + (t >> 2);       // 64 n-rows per block
    int k0 = blockIdx.y * 32 + (t & 3) * 8;    // 32 k per block, 8 per thread
    half8_t v;
#pragma unroll
    for (int j = 0; j < 8; ++j)
        v[j] = (_Float16)W[(size_t)(k0 + j) * N_SZ + n];
    *(half8_t*)(Wt + (size_t)n * K_SZ + k0) = v;
}

// ---------------------------------------------------------------------------
// Kernel 3: fused GEMM + sLSTM pointwise.
// Tile: 128 m x 128 cols where cols = [z|i|f|o] strips of 32 j each
// (sB rows r -> Wt row (r>>5)*2048 + j0 + (r&31)). Thread owning z(m,j) in
// acc[mi][nj] owns i,f,o(m,j) in acc[mi][nj+2/4/6] -> in-register fusion.
// LDS XOR swizzle: chunk c of row r lives at slot c ^ ((r>>1)&3)  => every
// fragment ds_read_b128 is 2-way bank aliased (free, m136).
// ---------------------------------------------------------------------------
__global__ __launch_bounds__(256)
void gemm_fused_kernel(const _Float16* __restrict__ A,
                       const _Float16* __restrict__ Wt,
                       const float* __restrict__ Bias,
                       const float* __restrict__ Cst,
                       const float* __restrict__ Nst,
                       const float* __restrict__ Mst,
                       float* __restrict__ out) {
    __shared__ _Float16 sA[128 * 32];
    __shared__ _Float16 sB[128 * 32];
    const int t    = threadIdx.x;
    const int wave = t >> 6;
    const int lane = t & 63;
    const int m0 = blockIdx.y * 128;
    const int j0 = blockIdx.x * 32;

    f32x4 acc[2][8] = {};

    // ---- staging lane mapping (store side of the XOR swizzle) ----
    const int srl   = lane >> 2;                        // sub-row 0..15
    const int chunk = (lane & 3) ^ ((lane >> 3) & 3);   // global k-chunk this lane fetches
    const int ar0 = wave * 16 + srl;                    // A row, issue 0 (0..63)
    const int br0 = wave * 16 + srl;                    // B tile-row, issue 0
    const int br1 = br0 + 64;                           // B tile-row, issue 1
    const int wrow0 = (br0 >> 5) * H_SZ + j0 + (br0 & 31);
    const int wrow1 = (br1 >> 5) * H_SZ + j0 + (br1 & 31);

    const _Float16* gA0 = A  + (size_t)(m0 + ar0) * K_SZ + chunk * 8;
    const _Float16* gA1 = gA0 + (size_t)64 * K_SZ;
    const _Float16* gB0 = Wt + (size_t)wrow0 * K_SZ + chunk * 8;
    const _Float16* gB1 = Wt + (size_t)wrow1 * K_SZ + chunk * 8;
    char* lA0 = (char*)sA + wave * 1024;
    char* lA1 = lA0 + 4096;
    char* lB0 = (char*)sB + wave * 1024;
    char* lB1 = lB0 + 4096;

    // ---- fragment read addresses (read side of the swizzle) ----
    const int lm   = lane & 15;
    const int slot = (lane >> 4) ^ ((lm >> 1) & 3);     // per-lane constant
    const _Float16* fA = sA + (wave * 32 + lm) * 32 + slot * 8;
    const _Float16* fB = sB + lm * 32 + slot * 8;

    for (int k0 = 0; k0 < K_SZ; k0 += 32) {
        async_load16(gA0 + k0, lA0);
        async_load16(gA1 + k0, lA1);
        async_load16(gB0 + k0, lB0);
        async_load16(gB1 + k0, lB1);
        __syncthreads();

        half8_t af[2], bf[8];
        af[0] = *(const half8_t*)(fA);
        af[1] = *(const half8_t*)(fA + 16 * 32);
#pragma unroll
        for (int ni = 0; ni < 8; ++ni)
            bf[ni] = *(const half8_t*)(fB + ni * 16 * 32);
#pragma unroll
        for (int mi = 0; mi < 2; ++mi)
#pragma unroll
            for (int ni = 0; ni < 8; ++ni)
                acc[mi][ni] = __builtin_amdgcn_mfma_f32_16x16x32_f16(
                    af[mi], bf[ni], acc[mi][ni], 0, 0, 0);
        __syncthreads();
    }

    // ---- fused epilogue: C/D layout col=lane&15, row=(lane>>4)*4+reg ----
    const int cr = (lane >> 4) * 4;
    const int cc = lane & 15;
    const size_t bh = (size_t)M_SZ * H_SZ;
#pragma unroll
    for (int mi = 0; mi < 2; ++mi) {
#pragma unroll
        for (int nj = 0; nj < 2; ++nj) {
            const int j = j0 + nj * 16 + cc;
            const float bz = Bias[j];
            const float bi = Bias[H_SZ + j];
            const float bff = Bias[2 * H_SZ + j];
            const float bo = Bias[3 * H_SZ + j];
#pragma unroll
            for (int r = 0; r < 4; ++r) {
                const int m = m0 + wave * 32 + mi * 16 + cr + r;
                const size_t off = (size_t)m * H_SZ + j;
                float z = acc[mi][nj][r]     + bz;
                float i = acc[mi][2 + nj][r] + bi;
                float f = acc[mi][4 + nj][r] + bff;
                float o = acc[mi][6 + nj][r] + bo;
                float z_t = 1.0f - 2.0f * frcp(fexp(2.0f * z) + 1.0f);
                float f_t = frcp(1.0f + fexp(-f));
                float o_t = frcp(1.0f + fexp(-o));
                float ls  = fminf(f, 0.0f) - flog1p(fexp(-fabsf(f)));
                float m_t = fmaxf(ls + Mst[off], i);
                float ip  = fexp(i - m_t);
                float c_t = f_t * Cst[off] + ip * z_t;
                float n_t = f_t * Nst[off] + ip;
                float h_t = o_t * c_t * frcp(n_t);
                out[off]          = h_t;
                out[bh + off]     = c_t;
                out[2 * bh + off] = n_t;
                out[3 * bh + off] = m_t;
            }
        }
    }
}

// ---------------------------------------------------------------------------
extern "C" void kernel_launch(void* const* d_in, const int* in_sizes, int n_in,
                              void* d_out, int out_size, void* d_ws, size_t ws_size,
                              hipStream_t stream) {
    const float* x    = (const float*)d_in[0];
    const float* h    = (const float*)d_in[1];
    const float* c    = (const float*)d_in[2];
    const float* n    = (const float*)d_in[3];
    const float* m    = (const float*)d_in[4];
    const float* W    = (const float*)d_in[5];
    const float* Bias = (const float*)d_in[6];
    float* out = (float*)d_out;

    // ws layout: Wt fp16 (64 MiB) | combined fp16 (32 MiB)
    const size_t WT_BYTES = (size_t)N_SZ * K_SZ * 2;
    const size_t A_BYTES  = (size_t)M_SZ * K_SZ * 2;
    if (ws_size < WT_BYTES + A_BYTES) return;

    char* ws = (char*)d_ws;
    _Float16* Wt = (_Float16*)ws;
    _Float16* A  = (_Float16*)(ws + WT_BYTES);

    cast_combined_kernel<<<16384, 256, 0, stream>>>(x, h, A);
    transpose_cast_W<<<dim3(128, 128), 256, 0, stream>>>(W, Wt);
    gemm_fused_kernel<<<dim3(64, 32), 256, 0, stream>>>(A, Wt, Bias, c, n, m, out);
}